// Round 1
// baseline (292.770 us; speedup 1.0000x reference)
//
#include <hip/hip_runtime.h>
#include <hip/hip_bf16.h>

// irreps: 512x0e + 256x1o + 128x2e ; x,out: [16384, 1920] fp32, weight: 344064 fp32
// Strategy: bf16 MFMA GEMM per block. Workgroup = TN rows x ALL output channels
// (x/out touch HBM exactly once; weights re-read from L2). d-interleave resolved
// during fp32->bf16 LDS staging. Scale 1/sqrt(mul) applied in fp32 epilogue.

typedef float  f32x4  __attribute__((ext_vector_type(4)));
typedef short  bf16x8 __attribute__((ext_vector_type(8)));

#define ROWLEN 1920

__device__ __forceinline__ unsigned short f2bf(float f) {
    union { float f; unsigned int u; } c; c.f = f;
    unsigned int u = c.u;
    u += 0x7fffu + ((u >> 16) & 1u);   // round-to-nearest-even
    return (unsigned short)(u >> 16);
}

// weight blocks are consecutive: [512*512][256*256][128*128] -> same elem offsets in bf16 ws
__global__ __launch_bounds__(256) void prep_weights(const float* __restrict__ w,
                                                    unsigned short* __restrict__ wt) {
    int g = blockIdx.x * 256 + threadIdx.x;
    if (g >= 344064) return;
    int base, sh;
    if      (g < 262144) { base = 0;      sh = 9; }   // mul=512
    else if (g < 327680) { base = 262144; sh = 8; }   // mul=256
    else                 { base = 327680; sh = 7; }   // mul=128
    int local = g - base;
    int u = local >> sh;              // input channel
    int v = local & ((1 << sh) - 1);  // output channel
    wt[base + (v << sh) + u] = f2bf(w[g]);   // Wt[v][u], K-contiguous
}

// MUL: channels, D: irrep dim, TN: rows per workgroup.
// Logical GEMM: C[(n,i), v] = sum_u x[n,u,i] * W[u,v]
template<int MUL, int D, int TN, int X_OFF, int WT_BASE>
__global__ __launch_bounds__(256) void seg_gemm(const float* __restrict__ x,
                                                const unsigned short* __restrict__ wt,
                                                float* __restrict__ out,
                                                float scale) {
    constexpr int KB      = 32;            // K per step (one MFMA K)
    constexpr int NSTEP   = MUL / KB;
    constexpr int M_LOG   = TN * D;        // logical rows in tile (mult of 16)
    constexpr int MT      = M_LOG / 16;    // 16-row MFMA tiles (for D>1, tile == component i)
    constexpr int WAVE_NT = MUL / 64;      // 16-col tiles per wave (4 waves cover MUL)
    constexpr int STRIDE  = KB + 8;        // 40 shorts = 80 B row: 16B-aligned, ~2-way banks
    constexpr int ROW_F   = KB * D;        // fp32 elems per x-row per K-step (contiguous!)
    constexpr int ROW_F4  = ROW_F / 4;
    constexpr int TOT_F4  = TN * ROW_F4;

    __shared__ unsigned short lds[M_LOG * STRIDE];

    const int tid  = threadIdx.x;
    const int wave = tid >> 6;
    const int lane = tid & 63;
    const int q    = lane >> 4;
    const int t16  = lane & 15;
    const int n0   = blockIdx.x * TN;

    f32x4 acc[MT][WAVE_NT];
#pragma unroll
    for (int a = 0; a < MT; ++a)
#pragma unroll
        for (int b = 0; b < WAVE_NT; ++b) acc[a][b] = (f32x4)0.0f;

    const float* __restrict__ xblk = x + X_OFF + n0 * ROWLEN;
    const unsigned short* __restrict__ wblk = wt + WT_BASE;
    const int vbase = wave * (WAVE_NT * 16) + t16;

    for (int ks = 0; ks < NSTEP; ++ks) {
        const int u0 = ks * KB;
        __syncthreads();   // protect LDS from prior-iteration readers
        // ---- stage A tile: contiguous fp32 -> bf16, de-interleave into K-contiguous LDS
        for (int idx = tid; idx < TOT_F4; idx += 256) {
            const int nl = idx / ROW_F4;
            const int c4 = (idx % ROW_F4) * 4;
            const f32x4 vv = *(const f32x4*)(xblk + nl * ROWLEN + u0 * D + c4);
            if (D == 1) {
                unsigned int lo = f2bf(vv[0]) | ((unsigned int)f2bf(vv[1]) << 16);
                unsigned int hi = f2bf(vv[2]) | ((unsigned int)f2bf(vv[3]) << 16);
                unsigned int* p = (unsigned int*)&lds[nl * STRIDE + c4];
                p[0] = lo; p[1] = hi;
            } else {
#pragma unroll
                for (int e = 0; e < 4; ++e) {
                    const int c = c4 + e;
                    const int u = c / D;     // const divisor -> magic mul
                    const int i = c % D;
                    lds[(i * TN + nl) * STRIDE + u] = f2bf(vv[e]);
                }
            }
        }
        __syncthreads();
        // ---- A frags from LDS (ds_read_b128), B frags straight from L2-resident Wt
        bf16x8 afr[MT];
#pragma unroll
        for (int tm = 0; tm < MT; ++tm)
            afr[tm] = *(const bf16x8*)&lds[(16 * tm + t16) * STRIDE + q * 8];
#pragma unroll
        for (int tv = 0; tv < WAVE_NT; ++tv) {
            const bf16x8 bfr = *(const bf16x8*)&wblk[(vbase + tv * 16) * MUL + u0 + q * 8];
#pragma unroll
            for (int tm = 0; tm < MT; ++tm)
                acc[tm][tv] = __builtin_amdgcn_mfma_f32_16x16x32_bf16(afr[tm], bfr, acc[tm][tv], 0, 0, 0);
        }
    }

    // ---- epilogue: C/D layout col=lane&15, row=q*4+r ; apply 1/sqrt(mul)
#pragma unroll
    for (int tm = 0; tm < MT; ++tm) {
#pragma unroll
        for (int tv = 0; tv < WAVE_NT; ++tv) {
            const int v = vbase + tv * 16;
#pragma unroll
            for (int r = 0; r < 4; ++r) {
                const int rit = q * 4 + r;
                const int nl   = (D == 1) ? (16 * tm + rit) : rit;
                const int comp = (D == 1) ? 0 : tm;
                out[(n0 + nl) * ROWLEN + X_OFF + v * D + comp] = acc[tm][tv][r] * scale;
            }
        }
    }
}

extern "C" void kernel_launch(void* const* d_in, const int* in_sizes, int n_in,
                              void* d_out, int out_size, void* d_ws, size_t ws_size,
                              hipStream_t stream) {
    const float* x = (const float*)d_in[0];
    const float* w = (const float*)d_in[1];
    float* out = (float*)d_out;
    unsigned short* wt = (unsigned short*)d_ws;   // 344064 bf16 = 688 KB

    hipLaunchKernelGGL(prep_weights, dim3((344064 + 255) / 256), dim3(256), 0, stream, w, wt);

    // block0: mul=512, d=1, TN=32 -> 512 wgs, per-wave 2x8 tiles (64 acc)
    hipLaunchKernelGGL((seg_gemm<512, 1, 32, 0, 0>),
                       dim3(16384 / 32), dim3(256), 0, stream, x, wt, out, 0.044194173824f);
    // block1: mul=256, d=3, TN=16 -> 1024 wgs, per-wave 3x4 tiles (48 acc)
    hipLaunchKernelGGL((seg_gemm<256, 3, 16, 512, 262144>),
                       dim3(16384 / 16), dim3(256), 0, stream, x, wt, out, 0.0625f);
    // block2: mul=128, d=5, TN=16 -> 1024 wgs, per-wave 5x2 tiles (40 acc)
    hipLaunchKernelGGL((seg_gemm<128, 5, 16, 1280, 327680>),
                       dim3(16384 / 16), dim3(256), 0, stream, x, wt, out, 0.088388347648f);
}